// Round 2
// baseline (520.970 us; speedup 1.0000x reference)
//
#include <hip/hip_runtime.h>
#include <math.h>

// N_MAX_L = [22,19,16,13], offsets [0,22,41,57], N_TOTAL=70
// W1: (4,4,22,32)  W2/W3: (4,4,32,32)  W4: (4,4,32,22)
#define BLK 256
#define NEDGE_MAX 400000

// ---------------- compaction ----------------

__global__ void k_zero(int* __restrict__ cnt) {
  if (threadIdx.x < 4) cnt[threadIdx.x] = 0;
}

__global__ void __launch_bounds__(BLK) k_compact(const int* __restrict__ spc, int n,
                                                 int* __restrict__ cnt,
                                                 int* __restrict__ lists) {
  const int i = blockIdx.x * BLK + threadIdx.x;
  const int lane = threadIdx.x & 63;
  const int s = (i < n) ? spc[i] : -1;
#pragma unroll
  for (int sp = 0; sp < 4; sp++) {
    unsigned long long mask = __ballot(s == sp);
    if (s == sp) {
      unsigned long long lower = mask & ((1ULL << lane) - 1ULL);
      const int rank = __popcll(lower);
      const int leader = (int)__builtin_ctzll(mask);
      int base = 0;
      if (lane == leader) base = atomicAdd(&cnt[sp], __popcll(mask));
      base = __shfl(base, leader, 64);
      lists[sp * NEDGE_MAX + base + rank] = i;
    }
  }
}

// ---------------- compute ----------------

template <int L, int NL, int OFF>
__device__ __forceinline__ void body(const float* __restrict__ r,
                                     const float* __restrict__ tbl,
                                     const float* __restrict__ W1,
                                     const float* __restrict__ W2,
                                     const float* __restrict__ W3,
                                     const float* __restrict__ W4,
                                     float* __restrict__ out,
                                     const int* __restrict__ cnt,
                                     const int* __restrict__ lists) {
  const int s = blockIdx.z;                 // uniform -> weights via scalar loads
  const int cs = cnt[s];
  const int i = blockIdx.x * BLK + threadIdx.x;
  if (i >= cs) return;
  const int e = lists[s * NEDGE_MAX + i];

  // uniform weight bases for this (l, s)
  const float* __restrict__ w1 = W1 + (size_t)(L * 4 + s) * (22 * 32);
  const float* __restrict__ w2 = W2 + (size_t)(L * 4 + s) * (32 * 32);
  const float* __restrict__ w3 = W3 + (size_t)(L * 4 + s) * (32 * 32);
  const float* __restrict__ w4 = W4 + (size_t)(L * 4 + s) * (32 * 22);

  // ---- spline eval ----
  const float rr = r[e];
  float xi = rr * (1023.0f / 5.0f);
  int idx = (int)floorf(xi);
  idx = idx < 0 ? 0 : (idx > 1022 ? 1022 : idx);
  const float frac = xi - (float)idx;
  const float omf = 1.0f - frac;
  const float* t0 = tbl + idx * 70 + OFF;

  float x[NL];
#pragma unroll
  for (int k = 0; k < NL; k++) x[k] = t0[k] * omf + t0[k + 70] * frac;

  float h0[32], h1[32];

  // ---- layer 1: h0 = silu(x @ W1[:NL]) ----
#pragma unroll
  for (int j = 0; j < 32; j++) h0[j] = 0.0f;
#pragma unroll
  for (int k = 0; k < NL; k++) {
    const float xk = x[k];
#pragma unroll
    for (int j = 0; j < 32; j++) h0[j] += xk * w1[k * 32 + j];
  }
#pragma unroll
  for (int j = 0; j < 32; j++) h0[j] = __fdividef(h0[j], 1.0f + __expf(-h0[j]));

  // ---- layer 2: h1 = silu(h0 @ W2) ----
#pragma unroll
  for (int j = 0; j < 32; j++) h1[j] = 0.0f;
#pragma unroll
  for (int k = 0; k < 32; k++) {
    const float hk = h0[k];
#pragma unroll
    for (int j = 0; j < 32; j++) h1[j] += hk * w2[k * 32 + j];
  }
#pragma unroll
  for (int j = 0; j < 32; j++) h1[j] = __fdividef(h1[j], 1.0f + __expf(-h1[j]));

  // ---- layer 3: h0 = silu(h1 @ W3) ----
#pragma unroll
  for (int j = 0; j < 32; j++) h0[j] = 0.0f;
#pragma unroll
  for (int k = 0; k < 32; k++) {
    const float hk = h1[k];
#pragma unroll
    for (int j = 0; j < 32; j++) h0[j] += hk * w3[k * 32 + j];
  }
#pragma unroll
  for (int j = 0; j < 32; j++) h0[j] = __fdividef(h0[j], 1.0f + __expf(-h0[j]));

  // ---- layer 4: y = h0 @ W4[:, :NL] ----
  float y[NL];
#pragma unroll
  for (int j = 0; j < NL; j++) y[j] = 0.0f;
#pragma unroll
  for (int k = 0; k < 32; k++) {
    const float hk = h0[k];
#pragma unroll
    for (int j = 0; j < NL; j++) y[j] += hk * w4[k * 22 + j];
  }

  float* o = out + (size_t)e * 70 + OFF;
#pragma unroll
  for (int j = 0; j < NL; j++) o[j] = y[j];
}

__global__ void __launch_bounds__(BLK) rb_compute(const float* __restrict__ r,
                                                  const float* __restrict__ tbl,
                                                  const float* __restrict__ W1,
                                                  const float* __restrict__ W2,
                                                  const float* __restrict__ W3,
                                                  const float* __restrict__ W4,
                                                  float* __restrict__ out,
                                                  const int* __restrict__ cnt,
                                                  const int* __restrict__ lists) {
  switch (blockIdx.y) {
    case 0: body<0, 22, 0>(r, tbl, W1, W2, W3, W4, out, cnt, lists); break;
    case 1: body<1, 19, 22>(r, tbl, W1, W2, W3, W4, out, cnt, lists); break;
    case 2: body<2, 16, 41>(r, tbl, W1, W2, W3, W4, out, cnt, lists); break;
    default: body<3, 13, 57>(r, tbl, W1, W2, W3, W4, out, cnt, lists); break;
  }
}

extern "C" void kernel_launch(void* const* d_in, const int* in_sizes, int n_in,
                              void* d_out, int out_size, void* d_ws, size_t ws_size,
                              hipStream_t stream) {
  const float* r = (const float*)d_in[0];
  const int* spc = (const int*)d_in[1];
  const float* tbl = (const float*)d_in[2];
  const float* W1 = (const float*)d_in[3];
  const float* W2 = (const float*)d_in[4];
  const float* W3 = (const float*)d_in[5];
  const float* W4 = (const float*)d_in[6];
  float* out = (float*)d_out;
  const int n = in_sizes[0];

  int* cnt = (int*)d_ws;                  // 4 ints
  int* lists = (int*)d_ws + 64;           // 4 * NEDGE_MAX ints (6.4 MB)

  hipLaunchKernelGGL(k_zero, dim3(1), dim3(64), 0, stream, cnt);

  const int nb = (n + BLK - 1) / BLK;
  hipLaunchKernelGGL(k_compact, dim3(nb), dim3(BLK), 0, stream, spc, n, cnt, lists);

  dim3 grid(nb, 4, 4);
  hipLaunchKernelGGL(rb_compute, grid, dim3(BLK), 0, stream, r, tbl, W1, W2, W3,
                     W4, out, cnt, lists);
}

// Round 3
// 224.934 us; speedup vs baseline: 2.3161x; 2.3161x over previous
//
#include <hip/hip_runtime.h>
#include <math.h>

// N_MAX_L = [22,19,16,13], offsets [0,22,41,57], N_TOTAL=70
// W1: (4,4,22,32)  W2/W3: (4,4,32,32)  W4: (4,4,32,22)
#define BLK 256
#define NEDGE_MAX 400000
#define BX 128

typedef __attribute__((ext_vector_type(8))) short short8;
typedef __attribute__((ext_vector_type(4))) float f32x4;

struct Frag { short8 v; };

__device__ __forceinline__ unsigned short f2bf(float f) {
  unsigned int u = __float_as_uint(f);
  unsigned int r = (u + 0x7fffu + ((u >> 16) & 1u)) >> 16;
  return (unsigned short)r;
}
__device__ __forceinline__ float bf2f(unsigned short h) {
  return __uint_as_float(((unsigned int)h) << 16);
}

// ---------------- compaction ----------------

__global__ void k_zero(int* __restrict__ cnt) {
  if (threadIdx.x < 4) cnt[threadIdx.x] = 0;
}

__global__ void __launch_bounds__(BLK) k_compact(const int* __restrict__ spc, int n,
                                                 int* __restrict__ cnt,
                                                 int* __restrict__ perm) {
  __shared__ int wcnt[4][4];   // [wave][species]
  __shared__ int wbase[4][4];  // [wave][species]
  const int tid = threadIdx.x;
  const int i = blockIdx.x * BLK + tid;
  const int lane = tid & 63;
  const int w = tid >> 6;
  const int s = (i < n) ? spc[i] : -1;

  int rank = 0;
#pragma unroll
  for (int sp = 0; sp < 4; sp++) {
    unsigned long long m = __ballot(s == sp);
    if (lane == 0) wcnt[w][sp] = __popcll(m);
    if (s == sp) rank = __popcll(m & ((1ULL << lane) - 1ULL));
  }
  __syncthreads();
  if (tid < 4) {
    const int c0 = wcnt[0][tid], c1 = wcnt[1][tid], c2 = wcnt[2][tid], c3 = wcnt[3][tid];
    const int b = atomicAdd(&cnt[tid], c0 + c1 + c2 + c3);
    wbase[0][tid] = b;
    wbase[1][tid] = b + c0;
    wbase[2][tid] = b + c0 + c1;
    wbase[3][tid] = b + c0 + c1 + c2;
  }
  __syncthreads();
  if (s >= 0) perm[s * NEDGE_MAX + wbase[w][s] + rank] = i;
}

// ---------------- MFMA compute ----------------

__device__ __forceinline__ void split_store(float v, int d, Frag& h, Frag& l) {
  unsigned short hb = f2bf(v);
  h.v[d] = (short)hb;
  l.v[d] = (short)f2bf(v - bf2f(hb));
}

__device__ __forceinline__ void do_layer(const Frag* Ah, const Frag* Al,
                                         const Frag& bh, const Frag& bl,
                                         f32x4& d0, f32x4& d1) {
  f32x4 z = {0.f, 0.f, 0.f, 0.f};
  d0 = __builtin_amdgcn_mfma_f32_16x16x32_bf16(Al[0].v, bh.v, z, 0, 0, 0);
  d0 = __builtin_amdgcn_mfma_f32_16x16x32_bf16(Ah[0].v, bl.v, d0, 0, 0, 0);
  d0 = __builtin_amdgcn_mfma_f32_16x16x32_bf16(Ah[0].v, bh.v, d0, 0, 0, 0);
  d1 = __builtin_amdgcn_mfma_f32_16x16x32_bf16(Al[1].v, bh.v, z, 0, 0, 0);
  d1 = __builtin_amdgcn_mfma_f32_16x16x32_bf16(Ah[1].v, bl.v, d1, 0, 0, 0);
  d1 = __builtin_amdgcn_mfma_f32_16x16x32_bf16(Ah[1].v, bh.v, d1, 0, 0, 0);
}

template <int L, int NL, int OFF>
__device__ void body(const float* __restrict__ r, const float* __restrict__ tbl,
                     const float* __restrict__ W1, const float* __restrict__ W2,
                     const float* __restrict__ W3, const float* __restrict__ W4,
                     float* __restrict__ out, const int* __restrict__ cnt,
                     const int* __restrict__ perm) {
  const int s = blockIdx.y & 3;
  const int count = cnt[s];
  if (count == 0) return;

  const int tid = threadIdx.x;
  const int lane = tid & 63;
  const int w = tid >> 6;
  const int c = lane & 15;  // edge column within tile
  const int g = lane >> 4;  // k-group

  const float* __restrict__ w1 = W1 + (size_t)(L * 4 + s) * (22 * 32);
  const float* __restrict__ w2 = W2 + (size_t)(L * 4 + s) * (32 * 32);
  const float* __restrict__ w3 = W3 + (size_t)(L * 4 + s) * (32 * 32);
  const float* __restrict__ w4 = W4 + (size_t)(L * 4 + s) * (32 * 22);

  // ---- build weight A-frags (A = W^T: A[row=j][k] = W[k][j]), hi/lo split ----
  Frag A1h[2], A1l[2], A2h[2], A2l[2], A3h[2], A3l[2], A4h[2], A4l[2];
#pragma unroll
  for (int jt = 0; jt < 2; jt++) {
    const int j = jt * 16 + c;
#pragma unroll
    for (int d = 0; d < 8; d++) {
      const int k = 8 * g + d;  // our (g,d)->k convention, consistent A & B
      float v1 = (k < NL) ? w1[k * 32 + j] : 0.f;
      split_store(v1, d, A1h[jt], A1l[jt]);
      float v2 = w2[k * 32 + j];
      split_store(v2, d, A2h[jt], A2l[jt]);
      float v3 = w3[k * 32 + j];
      split_store(v3, d, A3h[jt], A3l[jt]);
      float v4 = (j < NL) ? w4[k * 22 + j] : 0.f;
      split_store(v4, d, A4h[jt], A4l[jt]);
    }
  }

  // per-wave transpose scratch: [edge c][j], rows padded to 36 floats
  __shared__ float xpose[4][16 * 36];
  float* __restrict__ xp = &xpose[w][c * 36];

  const int sBase = s * NEDGE_MAX;

  for (int eb = blockIdx.x * 64 + w * 16; eb < count; eb += gridDim.x * 64) {
    const int ei = eb + c;
    const bool valid = ei < count;
    const int e = perm[sBase + (valid ? ei : count - 1)];

    // ---- spline eval for this edge, k = 8g+d slots ----
    const float rr = r[e];
    float xi = rr * (1023.0f / 5.0f);
    int idx = (int)floorf(xi);
    idx = idx < 0 ? 0 : (idx > 1022 ? 1022 : idx);
    const float frac = xi - (float)idx;
    const float omf = 1.0f - frac;
    const float* t0 = tbl + idx * 70 + OFF;

    Frag bh, bl;
#pragma unroll
    for (int d = 0; d < 8; d++) {
      const int k = 8 * g + d;
      float xv = 0.f;
      if (k < NL) xv = t0[k] * omf + t0[k + 70] * frac;
      split_store(xv, d, bh, bl);
    }

    f32x4 d0, d1;

    // ---- layer 1 ----
    do_layer(A1h, A1l, bh, bl, d0, d1);

    // ---- transitions: silu -> LDS transpose -> rebuild B frags ----
#pragma unroll
    for (int t = 0; t < 3; t++) {
#pragma unroll
      for (int i2 = 0; i2 < 4; i2++) {
        d0[i2] = __fdividef(d0[i2], 1.0f + __expf(-d0[i2]));
        d1[i2] = __fdividef(d1[i2], 1.0f + __expf(-d1[i2]));
      }
      *(f32x4*)(xp + 4 * g) = d0;        // j = 4g..4g+3
      *(f32x4*)(xp + 16 + 4 * g) = d1;   // j = 16+4g..16+4g+3
      __asm__ volatile("" ::: "memory");
      f32x4 q0 = *(const f32x4*)(xp + 8 * g);      // k = 8g..8g+3
      f32x4 q1 = *(const f32x4*)(xp + 8 * g + 4);  // k = 8g+4..8g+7
#pragma unroll
      for (int d = 0; d < 4; d++) {
        split_store(q0[d], d, bh, bl);
        split_store(q1[d], d + 4, bh, bl);
      }
      if (t == 0) do_layer(A2h, A2l, bh, bl, d0, d1);
      else if (t == 1) do_layer(A3h, A3l, bh, bl, d0, d1);
      else do_layer(A4h, A4l, bh, bl, d0, d1);
    }

    // ---- store y^T: lane holds rows j=4g+i (d0), 16+4g+i (d1) of edge e ----
    float* __restrict__ o = out + (size_t)e * 70 + OFF;
#pragma unroll
    for (int i2 = 0; i2 < 4; i2++) {
      const int j0 = 4 * g + i2;
      if (valid && j0 < NL) o[j0] = d0[i2];
      const int j1 = 16 + 4 * g + i2;
      if (valid && j1 < NL) o[j1] = d1[i2];
    }
  }
}

__global__ void __launch_bounds__(BLK) rb_mfma(const float* __restrict__ r,
                                               const float* __restrict__ tbl,
                                               const float* __restrict__ W1,
                                               const float* __restrict__ W2,
                                               const float* __restrict__ W3,
                                               const float* __restrict__ W4,
                                               float* __restrict__ out,
                                               const int* __restrict__ cnt,
                                               const int* __restrict__ perm) {
  switch (blockIdx.y >> 2) {
    case 0: body<0, 22, 0>(r, tbl, W1, W2, W3, W4, out, cnt, perm); break;
    case 1: body<1, 19, 22>(r, tbl, W1, W2, W3, W4, out, cnt, perm); break;
    case 2: body<2, 16, 41>(r, tbl, W1, W2, W3, W4, out, cnt, perm); break;
    default: body<3, 13, 57>(r, tbl, W1, W2, W3, W4, out, cnt, perm); break;
  }
}

extern "C" void kernel_launch(void* const* d_in, const int* in_sizes, int n_in,
                              void* d_out, int out_size, void* d_ws, size_t ws_size,
                              hipStream_t stream) {
  const float* r = (const float*)d_in[0];
  const int* spc = (const int*)d_in[1];
  const float* tbl = (const float*)d_in[2];
  const float* W1 = (const float*)d_in[3];
  const float* W2 = (const float*)d_in[4];
  const float* W3 = (const float*)d_in[5];
  const float* W4 = (const float*)d_in[6];
  float* out = (float*)d_out;
  const int n = in_sizes[0];

  int* cnt = (int*)d_ws;         // 4 ints
  int* perm = (int*)d_ws + 64;   // 4 * NEDGE_MAX ints

  hipLaunchKernelGGL(k_zero, dim3(1), dim3(64), 0, stream, cnt);

  const int nb = (n + BLK - 1) / BLK;
  hipLaunchKernelGGL(k_compact, dim3(nb), dim3(BLK), 0, stream, spc, n, cnt, perm);

  hipLaunchKernelGGL(rb_mfma, dim3(BX, 16), dim3(BLK), 0, stream, r, tbl, W1, W2,
                     W3, W4, out, cnt, perm);
}

// Round 4
// 212.169 us; speedup vs baseline: 2.4554x; 1.0602x over previous
//
#include <hip/hip_runtime.h>
#include <math.h>

// N_MAX_L = [22,19,16,13], offsets [0,22,41,57], N_TOTAL=70
// W1: (4,4,22,32)  W2/W3: (4,4,32,32)  W4: (4,4,32,22)
#define BLK 256
#define NEDGE_MAX 400000
#define BX 128

typedef __attribute__((ext_vector_type(8))) short short8;
typedef __attribute__((ext_vector_type(4))) float f32x4;

union Frag {
  short8 s;
  unsigned int u[4];
};

// ---------------- compaction ----------------

__global__ void k_zero(int* __restrict__ cnt) {
  if (threadIdx.x < 4) cnt[threadIdx.x] = 0;
}

__global__ void __launch_bounds__(BLK) k_compact(const int* __restrict__ spc, int n,
                                                 int* __restrict__ cnt,
                                                 int* __restrict__ perm) {
  __shared__ int wcnt[4][4];   // [wave][species]
  __shared__ int wbase[4][4];  // [wave][species]
  const int tid = threadIdx.x;
  const int i = blockIdx.x * BLK + tid;
  const int lane = tid & 63;
  const int w = tid >> 6;
  const int s = (i < n) ? spc[i] : -1;

  int rank = 0;
#pragma unroll
  for (int sp = 0; sp < 4; sp++) {
    unsigned long long m = __ballot(s == sp);
    if (lane == 0) wcnt[w][sp] = __popcll(m);
    if (s == sp) rank = __popcll(m & ((1ULL << lane) - 1ULL));
  }
  __syncthreads();
  if (tid < 4) {
    const int c0 = wcnt[0][tid], c1 = wcnt[1][tid], c2 = wcnt[2][tid], c3 = wcnt[3][tid];
    const int b = atomicAdd(&cnt[tid], c0 + c1 + c2 + c3);
    wbase[0][tid] = b;
    wbase[1][tid] = b + c0;
    wbase[2][tid] = b + c0 + c1;
    wbase[3][tid] = b + c0 + c1 + c2;
  }
  __syncthreads();
  if (s >= 0) perm[s * NEDGE_MAX + wbase[w][s] + rank] = i;
}

// ---------------- MFMA compute ----------------

// Truncation-based hi/lo bf16 split of a float pair, packed into one u32 each.
// slot even = low 16 bits, slot odd = high 16 bits (consistent for A and B).
__device__ __forceinline__ void split_pair(float a, float b, unsigned int& hi,
                                           unsigned int& lo) {
  const unsigned int ua = __float_as_uint(a);
  const unsigned int ub = __float_as_uint(b);
  const unsigned int ha = ua & 0xFFFF0000u;
  const unsigned int hb = ub & 0xFFFF0000u;
  hi = (ua >> 16) | hb;
  const float ra = a - __uint_as_float(ha);
  const float rb = b - __uint_as_float(hb);
  lo = (__float_as_uint(ra) >> 16) | (__float_as_uint(rb) & 0xFFFF0000u);
}

__device__ __forceinline__ void do_layer(const Frag* Ah, const Frag* Al,
                                         const Frag& bh, const Frag& bl,
                                         f32x4& d0, f32x4& d1) {
  f32x4 z = {0.f, 0.f, 0.f, 0.f};
  d0 = __builtin_amdgcn_mfma_f32_16x16x32_bf16(Al[0].s, bh.s, z, 0, 0, 0);
  d0 = __builtin_amdgcn_mfma_f32_16x16x32_bf16(Ah[0].s, bl.s, d0, 0, 0, 0);
  d0 = __builtin_amdgcn_mfma_f32_16x16x32_bf16(Ah[0].s, bh.s, d0, 0, 0, 0);
  d1 = __builtin_amdgcn_mfma_f32_16x16x32_bf16(Al[1].s, bh.s, z, 0, 0, 0);
  d1 = __builtin_amdgcn_mfma_f32_16x16x32_bf16(Ah[1].s, bl.s, d1, 0, 0, 0);
  d1 = __builtin_amdgcn_mfma_f32_16x16x32_bf16(Ah[1].s, bh.s, d1, 0, 0, 0);
}

__device__ __forceinline__ f32x4 silu4(f32x4 v) {
#pragma unroll
  for (int i = 0; i < 4; i++) v[i] = __fdividef(v[i], 1.0f + __expf(-v[i]));
  return v;
}

template <int L, int NL, int OFF>
__device__ void body(const float* __restrict__ r, const float* __restrict__ tbl,
                     const float* __restrict__ W1, const float* __restrict__ W2,
                     const float* __restrict__ W3, const float* __restrict__ W4,
                     float* __restrict__ out, const int* __restrict__ cnt,
                     const int* __restrict__ perm, float* __restrict__ xpw) {
  const int s = blockIdx.y & 3;
  const int count = cnt[s];
  if (count == 0) return;

  const int lane = threadIdx.x & 63;
  const int w = threadIdx.x >> 6;
  const int c = lane & 15;  // edge column within tile
  const int g = lane >> 4;  // k-group

  const float* __restrict__ w1 = W1 + (size_t)(L * 4 + s) * (22 * 32);
  const float* __restrict__ w2 = W2 + (size_t)(L * 4 + s) * (32 * 32);
  const float* __restrict__ w3 = W3 + (size_t)(L * 4 + s) * (32 * 32);
  const float* __restrict__ w4 = W4 + (size_t)(L * 4 + s) * (32 * 22);

  // ---- build weight A-frags (A = W^T: A[row=j][k] = W[k][j]), hi/lo split ----
  Frag A1h[2], A1l[2], A2h[2], A2l[2], A3h[2], A3l[2], A4h[2], A4l[2];
#pragma unroll
  for (int jt = 0; jt < 2; jt++) {
    const int j = jt * 16 + c;
#pragma unroll
    for (int p = 0; p < 4; p++) {
      const int k0 = 8 * g + 2 * p, k1 = k0 + 1;
      float a, b;
      a = (k0 < NL) ? w1[k0 * 32 + j] : 0.f;
      b = (k1 < NL) ? w1[k1 * 32 + j] : 0.f;
      split_pair(a, b, A1h[jt].u[p], A1l[jt].u[p]);
      a = w2[k0 * 32 + j];
      b = w2[k1 * 32 + j];
      split_pair(a, b, A2h[jt].u[p], A2l[jt].u[p]);
      a = w3[k0 * 32 + j];
      b = w3[k1 * 32 + j];
      split_pair(a, b, A3h[jt].u[p], A3l[jt].u[p]);
      a = (j < NL) ? w4[k0 * 22 + j] : 0.f;
      b = (j < NL) ? w4[k1 * 22 + j] : 0.f;
      split_pair(a, b, A4h[jt].u[p], A4l[jt].u[p]);
    }
  }

  // per-wave transpose scratch: [edge c][j], rows padded to 36 floats
  float* __restrict__ xp = xpw + c * 36;

  const int sBase = s * NEDGE_MAX;

  for (int eb = blockIdx.x * 64 + w * 16; eb < count; eb += gridDim.x * 64) {
    const int ei = eb + c;
    const bool valid = ei < count;
    const int e = perm[sBase + (valid ? ei : count - 1)];

    // ---- spline eval for this edge, k = 8g+d slots ----
    const float rr = r[e];
    float xi = rr * (1023.0f / 5.0f);
    int idx = (int)floorf(xi);
    idx = idx < 0 ? 0 : (idx > 1022 ? 1022 : idx);
    const float frac = xi - (float)idx;
    const float omf = 1.0f - frac;
    const float* t0 = tbl + idx * 70 + OFF;

    Frag bh, bl;
#pragma unroll
    for (int p = 0; p < 4; p++) {
      const int k0 = 8 * g + 2 * p, k1 = k0 + 1;
      float a = (k0 < NL) ? t0[k0] * omf + t0[k0 + 70] * frac : 0.f;
      float b = (k1 < NL) ? t0[k1] * omf + t0[k1 + 70] * frac : 0.f;
      split_pair(a, b, bh.u[p], bl.u[p]);
    }

    f32x4 d0, d1;

    // ---- layer 1 ----
    do_layer(A1h, A1l, bh, bl, d0, d1);

    // ---- transitions: silu -> LDS transpose -> rebuild B frags ----
#pragma unroll
    for (int t = 0; t < 3; t++) {
      d0 = silu4(d0);
      d1 = silu4(d1);
      *(f32x4*)(xp + 4 * g) = d0;       // j = 4g..4g+3
      *(f32x4*)(xp + 16 + 4 * g) = d1;  // j = 16+4g..16+4g+3
      __asm__ volatile("" ::: "memory");
      f32x4 q0 = *(const f32x4*)(xp + 8 * g);      // k = 8g..8g+3
      f32x4 q1 = *(const f32x4*)(xp + 8 * g + 4);  // k = 8g+4..8g+7
      split_pair(q0[0], q0[1], bh.u[0], bl.u[0]);
      split_pair(q0[2], q0[3], bh.u[1], bl.u[1]);
      split_pair(q1[0], q1[1], bh.u[2], bl.u[2]);
      split_pair(q1[2], q1[3], bh.u[3], bl.u[3]);
      if (t == 0) do_layer(A2h, A2l, bh, bl, d0, d1);
      else if (t == 1) do_layer(A3h, A3l, bh, bl, d0, d1);
      else do_layer(A4h, A4l, bh, bl, d0, d1);
    }

    // ---- store y^T: lane holds rows j=4g+i (d0), 16+4g+i (d1) of edge e ----
    float* __restrict__ o = out + (size_t)e * 70 + OFF;
#pragma unroll
    for (int i2 = 0; i2 < 4; i2++) {
      const int j0 = 4 * g + i2;
      if (valid && j0 < NL) o[j0] = d0[i2];
      const int j1 = 16 + 4 * g + i2;
      if (valid && j1 < NL) o[j1] = d1[i2];
    }
  }
}

__global__ void __launch_bounds__(BLK) rb_mfma(const float* __restrict__ r,
                                               const float* __restrict__ tbl,
                                               const float* __restrict__ W1,
                                               const float* __restrict__ W2,
                                               const float* __restrict__ W3,
                                               const float* __restrict__ W4,
                                               float* __restrict__ out,
                                               const int* __restrict__ cnt,
                                               const int* __restrict__ perm) {
  __shared__ float xpose[4][16 * 36];  // ONE allocation at kernel scope
  float* xpw = &xpose[threadIdx.x >> 6][0];
  switch (blockIdx.y >> 2) {
    case 0: body<0, 22, 0>(r, tbl, W1, W2, W3, W4, out, cnt, perm, xpw); break;
    case 1: body<1, 19, 22>(r, tbl, W1, W2, W3, W4, out, cnt, perm, xpw); break;
    case 2: body<2, 16, 41>(r, tbl, W1, W2, W3, W4, out, cnt, perm, xpw); break;
    default: body<3, 13, 57>(r, tbl, W1, W2, W3, W4, out, cnt, perm, xpw); break;
  }
}

extern "C" void kernel_launch(void* const* d_in, const int* in_sizes, int n_in,
                              void* d_out, int out_size, void* d_ws, size_t ws_size,
                              hipStream_t stream) {
  const float* r = (const float*)d_in[0];
  const int* spc = (const int*)d_in[1];
  const float* tbl = (const float*)d_in[2];
  const float* W1 = (const float*)d_in[3];
  const float* W2 = (const float*)d_in[4];
  const float* W3 = (const float*)d_in[5];
  const float* W4 = (const float*)d_in[6];
  float* out = (float*)d_out;
  const int n = in_sizes[0];

  int* cnt = (int*)d_ws;        // 4 ints
  int* perm = (int*)d_ws + 64;  // 4 * NEDGE_MAX ints

  hipLaunchKernelGGL(k_zero, dim3(1), dim3(64), 0, stream, cnt);

  const int nb = (n + BLK - 1) / BLK;
  hipLaunchKernelGGL(k_compact, dim3(nb), dim3(BLK), 0, stream, spc, n, cnt, perm);

  hipLaunchKernelGGL(rb_mfma, dim3(BX, 16), dim3(BLK), 0, stream, r, tbl, W1, W2,
                     W3, W4, out, cnt, perm);
}

// Round 5
// 162.495 us; speedup vs baseline: 3.2061x; 1.3057x over previous
//
#include <hip/hip_runtime.h>
#include <hip/hip_bf16.h>
#include <math.h>

// N_MAX_L = [22,19,16,13], offsets [0,22,41,57], N_TOTAL=70
// W1: (4,4,22,32)  W2/W3: (4,4,32,32)  W4: (4,4,32,22)
#define BLK 256
#define NEDGE_MAX 400000
#define BX 128
#define TSL 24608  // padded per-l table slice: 1024*24 + 32 floats (16B-aligned units)

typedef __attribute__((ext_vector_type(8))) short short8;
typedef __attribute__((ext_vector_type(4))) float f32x4;

union Frag {
  short8 s;
  unsigned int u[4];
};

// ---------------- compaction ----------------

__global__ void k_zero(int* __restrict__ cnt) {
  if (threadIdx.x < 4) cnt[threadIdx.x] = 0;
}

__global__ void __launch_bounds__(BLK) k_compact(const int* __restrict__ spc, int n,
                                                 int* __restrict__ cnt,
                                                 int* __restrict__ perm) {
  __shared__ int wcnt[4][4];
  __shared__ int wbase[4][4];
  const int tid = threadIdx.x;
  const int i = blockIdx.x * BLK + tid;
  const int lane = tid & 63;
  const int w = tid >> 6;
  const int s = (i < n) ? spc[i] : -1;

  int rank = 0;
#pragma unroll
  for (int sp = 0; sp < 4; sp++) {
    unsigned long long m = __ballot(s == sp);
    if (lane == 0) wcnt[w][sp] = __popcll(m);
    if (s == sp) rank = __popcll(m & ((1ULL << lane) - 1ULL));
  }
  __syncthreads();
  if (tid < 4) {
    const int c0 = wcnt[0][tid], c1 = wcnt[1][tid], c2 = wcnt[2][tid], c3 = wcnt[3][tid];
    const int b = atomicAdd(&cnt[tid], c0 + c1 + c2 + c3);
    wbase[0][tid] = b;
    wbase[1][tid] = b + c0;
    wbase[2][tid] = b + c0 + c1;
    wbase[3][tid] = b + c0 + c1 + c2;
  }
  __syncthreads();
  if (s >= 0) perm[s * NEDGE_MAX + wbase[w][s] + rank] = i;
}

// ---------------- padded table staging ----------------
// wt layout: [l][idx][24] (cols >= NL zeroed), plus 32-float zero tail per slice.

__global__ void __launch_bounds__(256) k_table(const float* __restrict__ tbl,
                                               float* __restrict__ wt) {
  const int t = blockIdx.x * 256 + threadIdx.x;
  if (t < 4 * 1024 * 24) {
    const int l = t / (1024 * 24);
    const int rem = t - l * (1024 * 24);
    const int idx = rem / 24;
    const int j = rem - idx * 24;
    const int off = (l == 0) ? 0 : (l == 1) ? 22 : (l == 2) ? 41 : 57;
    const int nl = (l == 0) ? 22 : (l == 1) ? 19 : (l == 2) ? 16 : 13;
    const float v = (j < nl) ? tbl[idx * 70 + off + j] : 0.f;
    wt[l * TSL + idx * 24 + j] = v;
  }
  if (t < 4 * 32) {
    const int l = t >> 5, j = t & 31;
    wt[l * TSL + 1024 * 24 + j] = 0.f;
  }
}

// ---------------- MFMA compute ----------------

// RNE hi/lo bf16 split of a float pair, packed into one u32 each.
// slot even = low 16 bits, slot odd = high 16 bits.
__device__ __forceinline__ void split_pair(float a, float b, unsigned int& hi,
                                           unsigned int& lo) {
  __hip_bfloat162 h2 = __float22bfloat162_rn(float2{a, b});
  const unsigned int h = *reinterpret_cast<unsigned int*>(&h2);
  hi = h;
  const float ra = a - __uint_as_float((h & 0xFFFFu) << 16);
  const float rb = b - __uint_as_float(h & 0xFFFF0000u);
  __hip_bfloat162 l2 = __float22bfloat162_rn(float2{ra, rb});
  lo = *reinterpret_cast<unsigned int*>(&l2);
}

__device__ __forceinline__ void do_layer(const Frag* Ah, const Frag* Al,
                                         const Frag& bh, const Frag& bl,
                                         f32x4& d0, f32x4& d1) {
  f32x4 z = {0.f, 0.f, 0.f, 0.f};
  d0 = __builtin_amdgcn_mfma_f32_16x16x32_bf16(Al[0].s, bh.s, z, 0, 0, 0);
  d0 = __builtin_amdgcn_mfma_f32_16x16x32_bf16(Ah[0].s, bl.s, d0, 0, 0, 0);
  d0 = __builtin_amdgcn_mfma_f32_16x16x32_bf16(Ah[0].s, bh.s, d0, 0, 0, 0);
  d1 = __builtin_amdgcn_mfma_f32_16x16x32_bf16(Al[1].s, bh.s, z, 0, 0, 0);
  d1 = __builtin_amdgcn_mfma_f32_16x16x32_bf16(Ah[1].s, bl.s, d1, 0, 0, 0);
  d1 = __builtin_amdgcn_mfma_f32_16x16x32_bf16(Ah[1].s, bh.s, d1, 0, 0, 0);
}

__device__ __forceinline__ f32x4 silu4(f32x4 v) {
#pragma unroll
  for (int i = 0; i < 4; i++) v[i] = __fdividef(v[i], 1.0f + __expf(-v[i]));
  return v;
}

struct GD {
  f32x4 a0, a1, b0, b1;  // row idx: k=8g..8g+7 ; row idx+1: same
  float frac;
  int e;
  int valid;
};

__device__ __forceinline__ GD do_gather(const float* __restrict__ r,
                                        const float* __restrict__ tb,
                                        const int* __restrict__ perm, int sBase,
                                        int ei, int count) {
  GD gd;
  gd.valid = ei < count;
  const int eic = gd.valid ? ei : count - 1;
  gd.e = perm[sBase + eic];
  const float rr = r[gd.e];
  const float xi = rr * (1023.0f / 5.0f);
  int idx = (int)floorf(xi);
  idx = idx < 0 ? 0 : (idx > 1022 ? 1022 : idx);
  gd.frac = xi - (float)idx;
  const float* t0 = tb + idx * 24;  // tb already includes l-slice + 8g
  gd.a0 = *(const f32x4*)(t0);
  gd.a1 = *(const f32x4*)(t0 + 4);
  gd.b0 = *(const f32x4*)(t0 + 24);
  gd.b1 = *(const f32x4*)(t0 + 28);
  return gd;
}

template <int L, int NL, int OFF>
__device__ void body(const float* __restrict__ r, const float* __restrict__ wt,
                     const float* __restrict__ W1, const float* __restrict__ W2,
                     const float* __restrict__ W3, const float* __restrict__ W4,
                     float* __restrict__ out, const int* __restrict__ cnt,
                     const int* __restrict__ perm) {
  const int s = blockIdx.y & 3;
  const int count = cnt[s];
  if (count == 0) return;

  const int lane = threadIdx.x & 63;
  const int w = threadIdx.x >> 6;
  const int c = lane & 15;  // edge column within tile
  const int g = lane >> 4;  // k-group

  const float* __restrict__ w1 = W1 + (size_t)(L * 4 + s) * (22 * 32);
  const float* __restrict__ w2 = W2 + (size_t)(L * 4 + s) * (32 * 32);
  const float* __restrict__ w3 = W3 + (size_t)(L * 4 + s) * (32 * 32);
  const float* __restrict__ w4 = W4 + (size_t)(L * 4 + s) * (32 * 22);

  // A-frags: A = W^T (rows=out features j). W1 uses standard k = 8g+d (matches
  // the gather-built B). W2/W3/W4 use the PERMUTED k'(g,d) = (d<4 ? 4g+d :
  // 16+4g+d-4) so the previous layer's D-register layout feeds the next MFMA
  // directly -- no transpose, no LDS. (Legal: MFMA pairs A-slot(g,d) with
  // B-slot(g,d); any k-relabeling applied to BOTH operands is an identity.)
  Frag A1h[2], A1l[2], A2h[2], A2l[2], A3h[2], A3l[2], A4h[2], A4l[2];
#pragma unroll
  for (int jt = 0; jt < 2; jt++) {
    const int j = jt * 16 + c;
#pragma unroll
    for (int p = 0; p < 4; p++) {
      const int k0 = 8 * g + 2 * p, k1 = k0 + 1;
      float a = (k0 < NL) ? w1[k0 * 32 + j] : 0.f;
      float b = (k1 < NL) ? w1[k1 * 32 + j] : 0.f;
      split_pair(a, b, A1h[jt].u[p], A1l[jt].u[p]);
      const int kp0 = (p < 2) ? (4 * g + 2 * p) : (16 + 4 * g + 2 * (p - 2));
      const int kp1 = kp0 + 1;
      split_pair(w2[kp0 * 32 + j], w2[kp1 * 32 + j], A2h[jt].u[p], A2l[jt].u[p]);
      split_pair(w3[kp0 * 32 + j], w3[kp1 * 32 + j], A3h[jt].u[p], A3l[jt].u[p]);
      a = (j < NL) ? w4[kp0 * 22 + j] : 0.f;
      b = (j < NL) ? w4[kp1 * 22 + j] : 0.f;
      split_pair(a, b, A4h[jt].u[p], A4l[jt].u[p]);
    }
  }

  const float* __restrict__ tb = wt + L * TSL + 8 * g;
  const int sBase = s * NEDGE_MAX;
  const int stride = gridDim.x * 64;

  int eb = blockIdx.x * 64 + w * 16;
  GD cur = do_gather(r, tb, perm, sBase, eb + c, count);

  for (; eb < count; eb += stride) {
    // prefetch next tile's gather (independent -> overlaps the MFMA chain)
    GD nxt = do_gather(r, tb, perm, sBase, eb + stride + c, count);

    // ---- build layer-1 B frags (standard k = 8g+d). Pad cols [NL,24) are
    // zero in both rows -> lerp gives 0; g==3 overflow slots (k>=24) are
    // multiplied by zeroed A1 slots, so no masking needed. ----
    Frag bh, bl;
    {
      float x[8];
#pragma unroll
      for (int d = 0; d < 4; d++) {
        x[d] = cur.a0[d] + cur.frac * (cur.b0[d] - cur.a0[d]);
        x[d + 4] = cur.a1[d] + cur.frac * (cur.b1[d] - cur.a1[d]);
      }
      split_pair(x[0], x[1], bh.u[0], bl.u[0]);
      split_pair(x[2], x[3], bh.u[1], bl.u[1]);
      split_pair(x[4], x[5], bh.u[2], bl.u[2]);
      split_pair(x[6], x[7], bh.u[3], bl.u[3]);
    }

    f32x4 d0, d1;
    do_layer(A1h, A1l, bh, bl, d0, d1);

    // ---- transitions: silu -> in-register repack (k'-mapping) -> next layer ----
#pragma unroll
    for (int t = 0; t < 3; t++) {
      d0 = silu4(d0);
      d1 = silu4(d1);
      split_pair(d0[0], d0[1], bh.u[0], bl.u[0]);
      split_pair(d0[2], d0[3], bh.u[1], bl.u[1]);
      split_pair(d1[0], d1[1], bh.u[2], bl.u[2]);
      split_pair(d1[2], d1[3], bh.u[3], bl.u[3]);
      if (t == 0) do_layer(A2h, A2l, bh, bl, d0, d1);
      else if (t == 1) do_layer(A3h, A3l, bh, bl, d0, d1);
      else do_layer(A4h, A4l, bh, bl, d0, d1);
    }

    // ---- store y^T: lane holds rows j=4g+i (d0), 16+4g+i (d1) of edge e ----
    float* __restrict__ o = out + (size_t)cur.e * 70 + OFF;
#pragma unroll
    for (int i2 = 0; i2 < 4; i2++) {
      const int j0 = 4 * g + i2;
      if (cur.valid && j0 < NL) o[j0] = d0[i2];
      const int j1 = 16 + 4 * g + i2;
      if (cur.valid && j1 < NL) o[j1] = d1[i2];
    }

    cur = nxt;
  }
}

__global__ void __launch_bounds__(BLK) rb_mfma(const float* __restrict__ r,
                                               const float* __restrict__ wt,
                                               const float* __restrict__ W1,
                                               const float* __restrict__ W2,
                                               const float* __restrict__ W3,
                                               const float* __restrict__ W4,
                                               float* __restrict__ out,
                                               const int* __restrict__ cnt,
                                               const int* __restrict__ perm) {
  switch (blockIdx.y >> 2) {
    case 0: body<0, 22, 0>(r, wt, W1, W2, W3, W4, out, cnt, perm); break;
    case 1: body<1, 19, 22>(r, wt, W1, W2, W3, W4, out, cnt, perm); break;
    case 2: body<2, 16, 41>(r, wt, W1, W2, W3, W4, out, cnt, perm); break;
    default: body<3, 13, 57>(r, wt, W1, W2, W3, W4, out, cnt, perm); break;
  }
}

extern "C" void kernel_launch(void* const* d_in, const int* in_sizes, int n_in,
                              void* d_out, int out_size, void* d_ws, size_t ws_size,
                              hipStream_t stream) {
  const float* r = (const float*)d_in[0];
  const int* spc = (const int*)d_in[1];
  const float* tbl = (const float*)d_in[2];
  const float* W1 = (const float*)d_in[3];
  const float* W2 = (const float*)d_in[4];
  const float* W3 = (const float*)d_in[5];
  const float* W4 = (const float*)d_in[6];
  float* out = (float*)d_out;
  const int n = in_sizes[0];

  int* cnt = (int*)d_ws;                              // 4 ints
  int* perm = (int*)d_ws + 64;                        // 4 * NEDGE_MAX ints
  float* wtbl = (float*)((int*)d_ws + 64 + 4 * NEDGE_MAX);  // 4*TSL floats, 16B-aligned

  hipLaunchKernelGGL(k_zero, dim3(1), dim3(64), 0, stream, cnt);

  const int nb = (n + BLK - 1) / BLK;
  hipLaunchKernelGGL(k_compact, dim3(nb), dim3(BLK), 0, stream, spc, n, cnt, perm);

  hipLaunchKernelGGL(k_table, dim3((4 * 1024 * 24 + 255) / 256), dim3(256), 0,
                     stream, tbl, wtbl);

  hipLaunchKernelGGL(rb_mfma, dim3(BX, 16), dim3(BLK), 0, stream, r, wtbl, W1, W2,
                     W3, W4, out, cnt, perm);
}

// Round 6
// 157.889 us; speedup vs baseline: 3.2996x; 1.0292x over previous
//
#include <hip/hip_runtime.h>
#include <hip/hip_bf16.h>
#include <math.h>

// N_MAX_L = [22,19,16,13], offsets [0,22,41,57], N_TOTAL=70
// W1: (4,4,22,32)  W2/W3: (4,4,32,32)  W4: (4,4,32,22)
#define BLK 256
#define NEDGE_MAX 400000
#define BX 128
#define TSL 24608  // padded per-l table slice: 1024*24 + 32 floats

typedef __attribute__((ext_vector_type(8))) short short8;
typedef __attribute__((ext_vector_type(4))) float f32x4;

union Frag {
  short8 s;
  unsigned int u[4];
};

// ---------------- compaction ----------------

__global__ void k_zero(int* __restrict__ cnt) {
  if (threadIdx.x < 4) cnt[threadIdx.x] = 0;
}

__global__ void __launch_bounds__(BLK) k_compact(const int* __restrict__ spc, int n,
                                                 int* __restrict__ cnt,
                                                 int* __restrict__ perm) {
  __shared__ int wcnt[4][4];
  __shared__ int wbase[4][4];
  const int tid = threadIdx.x;
  const int i = blockIdx.x * BLK + tid;
  const int lane = tid & 63;
  const int w = tid >> 6;
  const int s = (i < n) ? spc[i] : -1;

  int rank = 0;
#pragma unroll
  for (int sp = 0; sp < 4; sp++) {
    unsigned long long m = __ballot(s == sp);
    if (lane == 0) wcnt[w][sp] = __popcll(m);
    if (s == sp) rank = __popcll(m & ((1ULL << lane) - 1ULL));
  }
  __syncthreads();
  if (tid < 4) {
    const int c0 = wcnt[0][tid], c1 = wcnt[1][tid], c2 = wcnt[2][tid], c3 = wcnt[3][tid];
    const int b = atomicAdd(&cnt[tid], c0 + c1 + c2 + c3);
    wbase[0][tid] = b;
    wbase[1][tid] = b + c0;
    wbase[2][tid] = b + c0 + c1;
    wbase[3][tid] = b + c0 + c1 + c2;
  }
  __syncthreads();
  if (s >= 0) perm[s * NEDGE_MAX + wbase[w][s] + rank] = i;
}

// ---------------- padded table staging ----------------

__global__ void __launch_bounds__(256) k_table(const float* __restrict__ tbl,
                                               float* __restrict__ wt) {
  const int t = blockIdx.x * 256 + threadIdx.x;
  if (t < 4 * 1024 * 24) {
    const int l = t / (1024 * 24);
    const int rem = t - l * (1024 * 24);
    const int idx = rem / 24;
    const int j = rem - idx * 24;
    const int off = (l == 0) ? 0 : (l == 1) ? 22 : (l == 2) ? 41 : 57;
    const int nl = (l == 0) ? 22 : (l == 1) ? 19 : (l == 2) ? 16 : 13;
    const float v = (j < nl) ? tbl[idx * 70 + off + j] : 0.f;
    wt[l * TSL + idx * 24 + j] = v;
  }
  if (t < 4 * 32) {
    const int l = t >> 5, j = t & 31;
    wt[l * TSL + 1024 * 24 + j] = 0.f;
  }
}

// ---------------- MFMA compute ----------------

__device__ __forceinline__ void split_pair(float a, float b, unsigned int& hi,
                                           unsigned int& lo) {
  __hip_bfloat162 h2 = __float22bfloat162_rn(float2{a, b});
  const unsigned int h = *reinterpret_cast<unsigned int*>(&h2);
  hi = h;
  const float ra = a - __uint_as_float((h & 0xFFFFu) << 16);
  const float rb = b - __uint_as_float(h & 0xFFFF0000u);
  __hip_bfloat162 l2 = __float22bfloat162_rn(float2{ra, rb});
  lo = *reinterpret_cast<unsigned int*>(&l2);
}

__device__ __forceinline__ void do_layer(const Frag* Ah, const Frag* Al,
                                         const Frag& bh, const Frag& bl,
                                         f32x4& d0, f32x4& d1) {
  f32x4 z = {0.f, 0.f, 0.f, 0.f};
  d0 = __builtin_amdgcn_mfma_f32_16x16x32_bf16(Al[0].s, bh.s, z, 0, 0, 0);
  d0 = __builtin_amdgcn_mfma_f32_16x16x32_bf16(Ah[0].s, bl.s, d0, 0, 0, 0);
  d0 = __builtin_amdgcn_mfma_f32_16x16x32_bf16(Ah[0].s, bh.s, d0, 0, 0, 0);
  d1 = __builtin_amdgcn_mfma_f32_16x16x32_bf16(Al[1].s, bh.s, z, 0, 0, 0);
  d1 = __builtin_amdgcn_mfma_f32_16x16x32_bf16(Ah[1].s, bl.s, d1, 0, 0, 0);
  d1 = __builtin_amdgcn_mfma_f32_16x16x32_bf16(Ah[1].s, bh.s, d1, 0, 0, 0);
}

__device__ __forceinline__ f32x4 silu4(f32x4 v) {
#pragma unroll
  for (int i = 0; i < 4; i++) v[i] = __fdividef(v[i], 1.0f + __expf(-v[i]));
  return v;
}

struct GD {
  f32x4 a0, a1, b0, b1;
  float frac;
  int e;
  int valid;
};

__device__ __forceinline__ GD do_gather(const float* __restrict__ r,
                                        const float* __restrict__ tb,
                                        const int* __restrict__ perm, int sBase,
                                        int ei, int count) {
  GD gd;
  gd.valid = ei < count;
  const int eic = gd.valid ? ei : count - 1;
  gd.e = perm[sBase + eic];
  const float rr = r[gd.e];
  const float xi = rr * (1023.0f / 5.0f);
  int idx = (int)floorf(xi);
  idx = idx < 0 ? 0 : (idx > 1022 ? 1022 : idx);
  gd.frac = xi - (float)idx;
  const float* t0 = tb + idx * 24;
  gd.a0 = *(const f32x4*)(t0);
  gd.a1 = *(const f32x4*)(t0 + 4);
  gd.b0 = *(const f32x4*)(t0 + 24);
  gd.b1 = *(const f32x4*)(t0 + 28);
  return gd;
}

template <int L, int NL, int OFF>
__device__ void body(const float* __restrict__ r, const float* __restrict__ wt,
                     const float* __restrict__ W1, const float* __restrict__ W2,
                     const float* __restrict__ W3, const float* __restrict__ W4,
                     float* __restrict__ out, const int* __restrict__ cnt,
                     const int* __restrict__ perm, float* __restrict__ xpw,
                     int* __restrict__ eidw) {
  const int s = blockIdx.y & 3;
  const int count = cnt[s];
  if (count == 0) return;

  const int lane = threadIdx.x & 63;
  const int w = threadIdx.x >> 6;
  const int c = lane & 15;  // edge column within tile
  const int g = lane >> 4;  // k-group

  const float* __restrict__ w1 = W1 + (size_t)(L * 4 + s) * (22 * 32);
  const float* __restrict__ w2 = W2 + (size_t)(L * 4 + s) * (32 * 32);
  const float* __restrict__ w3 = W3 + (size_t)(L * 4 + s) * (32 * 32);
  const float* __restrict__ w4 = W4 + (size_t)(L * 4 + s) * (32 * 22);

  // A-frags: W1 standard k=8g+d; W2/W3/W4 permuted k'(g,d) so the previous
  // layer's D-register layout feeds the next MFMA directly (no transpose).
  Frag A1h[2], A1l[2], A2h[2], A2l[2], A3h[2], A3l[2], A4h[2], A4l[2];
#pragma unroll
  for (int jt = 0; jt < 2; jt++) {
    const int j = jt * 16 + c;
#pragma unroll
    for (int p = 0; p < 4; p++) {
      const int k0 = 8 * g + 2 * p, k1 = k0 + 1;
      float a = (k0 < NL) ? w1[k0 * 32 + j] : 0.f;
      float b = (k1 < NL) ? w1[k1 * 32 + j] : 0.f;
      split_pair(a, b, A1h[jt].u[p], A1l[jt].u[p]);
      const int kp0 = (p < 2) ? (4 * g + 2 * p) : (16 + 4 * g + 2 * (p - 2));
      const int kp1 = kp0 + 1;
      split_pair(w2[kp0 * 32 + j], w2[kp1 * 32 + j], A2h[jt].u[p], A2l[jt].u[p]);
      split_pair(w3[kp0 * 32 + j], w3[kp1 * 32 + j], A3h[jt].u[p], A3l[jt].u[p]);
      a = (j < NL) ? w4[kp0 * 22 + j] : 0.f;
      b = (j < NL) ? w4[kp1 * 22 + j] : 0.f;
      split_pair(a, b, A4h[jt].u[p], A4l[jt].u[p]);
    }
  }

  const float* __restrict__ tb = wt + L * TSL + 8 * g;
  const int sBase = s * NEDGE_MAX;
  const int stride = gridDim.x * 64;

  int eb = blockIdx.x * 64 + w * 16;
  GD cur = do_gather(r, tb, perm, sBase, eb + c, count);

  for (; eb < count; eb += stride) {
    GD nxt = do_gather(r, tb, perm, sBase, eb + stride + c, count);

    // ---- layer-1 B frags (standard k = 8g+d; pads are zero) ----
    Frag bh, bl;
    {
      float x[8];
#pragma unroll
      for (int d = 0; d < 4; d++) {
        x[d] = cur.a0[d] + cur.frac * (cur.b0[d] - cur.a0[d]);
        x[d + 4] = cur.a1[d] + cur.frac * (cur.b1[d] - cur.a1[d]);
      }
      split_pair(x[0], x[1], bh.u[0], bl.u[0]);
      split_pair(x[2], x[3], bh.u[1], bl.u[1]);
      split_pair(x[4], x[5], bh.u[2], bl.u[2]);
      split_pair(x[6], x[7], bh.u[3], bl.u[3]);
    }

    f32x4 d0, d1;
    do_layer(A1h, A1l, bh, bl, d0, d1);

#pragma unroll
    for (int t = 0; t < 3; t++) {
      d0 = silu4(d0);
      d1 = silu4(d1);
      split_pair(d0[0], d0[1], bh.u[0], bl.u[0]);
      split_pair(d0[2], d0[3], bh.u[1], bl.u[1]);
      split_pair(d1[0], d1[1], bh.u[2], bl.u[2]);
      split_pair(d1[2], d1[3], bh.u[3], bl.u[3]);
      if (t == 0) do_layer(A2h, A2l, bh, bl, d0, d1);
      else if (t == 1) do_layer(A3h, A3l, bh, bl, d0, d1);
      else do_layer(A4h, A4l, bh, bl, d0, d1);
    }

    // ---- coalesced epilogue: y^T -> per-wave LDS tile -> row-segment stores ----
    *(f32x4*)(xpw + c * 36 + 4 * g) = d0;       // features 4g..4g+3
    *(f32x4*)(xpw + c * 36 + 16 + 4 * g) = d1;  // features 16+4g..19+4g
    if (g == 0) eidw[c] = cur.valid ? cur.e : -1;
    __asm__ volatile("" ::: "memory");

    constexpr int TOT = 16 * NL;
#pragma unroll
    for (int t = 0; t < (TOT + 63) / 64; t++) {
      const int flat = t * 64 + lane;
      if (flat < TOT) {
        const int row = flat / NL;  // NL is constexpr -> magic-mul
        const int f = flat - row * NL;
        const int er = eidw[row];
        if (er >= 0) out[(size_t)er * 70 + OFF + f] = xpw[row * 36 + f];
      }
    }
    __asm__ volatile("" ::: "memory");

    cur = nxt;
  }
}

__global__ void __launch_bounds__(BLK) rb_mfma(const float* __restrict__ r,
                                               const float* __restrict__ wt,
                                               const float* __restrict__ W1,
                                               const float* __restrict__ W2,
                                               const float* __restrict__ W3,
                                               const float* __restrict__ W4,
                                               float* __restrict__ out,
                                               const int* __restrict__ cnt,
                                               const int* __restrict__ perm) {
  __shared__ float xpose[4][16 * 36];
  __shared__ int eidt[4][16];
  const int w = threadIdx.x >> 6;
  float* xpw = &xpose[w][0];
  int* eidw = &eidt[w][0];
  switch (blockIdx.y >> 2) {
    case 0: body<0, 22, 0>(r, wt, W1, W2, W3, W4, out, cnt, perm, xpw, eidw); break;
    case 1: body<1, 19, 22>(r, wt, W1, W2, W3, W4, out, cnt, perm, xpw, eidw); break;
    case 2: body<2, 16, 41>(r, wt, W1, W2, W3, W4, out, cnt, perm, xpw, eidw); break;
    default: body<3, 13, 57>(r, wt, W1, W2, W3, W4, out, cnt, perm, xpw, eidw); break;
  }
}

extern "C" void kernel_launch(void* const* d_in, const int* in_sizes, int n_in,
                              void* d_out, int out_size, void* d_ws, size_t ws_size,
                              hipStream_t stream) {
  const float* r = (const float*)d_in[0];
  const int* spc = (const int*)d_in[1];
  const float* tbl = (const float*)d_in[2];
  const float* W1 = (const float*)d_in[3];
  const float* W2 = (const float*)d_in[4];
  const float* W3 = (const float*)d_in[5];
  const float* W4 = (const float*)d_in[6];
  float* out = (float*)d_out;
  const int n = in_sizes[0];

  int* cnt = (int*)d_ws;
  int* perm = (int*)d_ws + 64;
  float* wtbl = (float*)((int*)d_ws + 64 + 4 * NEDGE_MAX);

  hipLaunchKernelGGL(k_zero, dim3(1), dim3(64), 0, stream, cnt);

  const int nb = (n + BLK - 1) / BLK;
  hipLaunchKernelGGL(k_compact, dim3(nb), dim3(BLK), 0, stream, spc, n, cnt, perm);

  hipLaunchKernelGGL(k_table, dim3((4 * 1024 * 24 + 255) / 256), dim3(256), 0,
                     stream, tbl, wtbl);

  hipLaunchKernelGGL(rb_mfma, dim3(BX, 16), dim3(BLK), 0, stream, r, wtbl, W1, W2,
                     W3, W4, out, cnt, perm);
}